// Round 4
// baseline (1571.534 us; speedup 1.0000x reference)
//
#include <hip/hip_runtime.h>

// OU scan, single-pass chained scan with decoupled lookback (ticket-based).
// x_s = c_s * x_{s-1} + sqrt(1-c_s^2) * z_s,  c_s = exp(-theta*dt_s)
// B=64, S=4096, D=256, f32.
//
// z is read from HBM exactly once (268 MB read + 268 MB write ~ 83 us floor).
// Block grabs a ticket T (global atomic); T -> (b = T/NC, k = T%NC) chunk of
// 128 rows. Thread owns one d-column; chunk z lives in 128 VGPRs, is
// local-scanned in place; inter-chunk carry E arrives via lookback over
// published per-chunk aggregates/inclusives; apply is x_r = local_r + P_r*E
// (P_r telescoped from t, no z re-read).
//
// Progress under ANY dispatch order (G16): ticket T only waits on tickets
// < T, which were grabbed by blocks that are already resident and running;
// ticket with k==0 waits on nothing -> induction terminates.
//
// Ordering protocol (the round-3 bug): payload stores (agent relaxed) ->
// __threadfence() per wave -> __syncthreads() -> flag store RELEASE;
// consumer spins on flag with ACQUIRE, then relaxed agent payload loads.

#define THETA 0.5f
constexpr int Bn = 64;
constexpr int Sn = 4096;
constexpr int Dn = 256;
constexpr int CHUNK = 128;
constexpr int NC   = Sn / CHUNK;     // 32 chunks per batch
constexpr int NTICK = Bn * NC;       // 2048 tickets
constexpr int NBLK = 512;            // 2 blocks/CU x 256 CU

__global__ __launch_bounds__(256, 2) void k_ou(
    const float* __restrict__ t,     // [B,S]
    const float* __restrict__ x0,    // [B,D]
    const float* __restrict__ z,     // [B,S,D]
    float* __restrict__ out,         // [B,S,D]
    float* __restrict__ agg,         // ws [NTICK][D]
    float* __restrict__ inc,         // ws [NTICK][D]
    unsigned* __restrict__ flags,    // ws [NTICK] 0=none 1=agg 2=inclusive
    unsigned* __restrict__ ticket)   // ws [1]
{
    const int d = threadIdx.x;
    __shared__ float cs[CHUNK], ss[CHUNK], Ps[CHUNK];
    __shared__ float As[NC];
    __shared__ unsigned tks;

    for (;;) {
        __syncthreads();             // protect LDS + tks from previous ticket
        if (d == 0)
            tks = __hip_atomic_fetch_add(ticket, 1u, __ATOMIC_RELAXED,
                                         __HIP_MEMORY_SCOPE_AGENT);
        __syncthreads();
        const unsigned T = tks;      // block-uniform
        if (T >= NTICK) return;
        const int b  = (int)(T / NC);
        const int k  = (int)(T % NC);
        const int s0 = k * CHUNK;
        const float* tb = t + (size_t)b * Sn;

        // per-chunk coefficients (threads 0..127: rows; 128..159: chunk decays)
        if (d < CHUNK) {
            const int r = d;
            const float tc   = tb[s0 + r];
            const float tp   = (s0 + r == 0) ? 0.0f : tb[s0 + r - 1];
            const float tpre = (s0 == 0) ? 0.0f : tb[s0 - 1];
            const float c = __expf(-THETA * (tc - tp));
            cs[r] = c;
            ss[r] = sqrtf(fmaxf(0.0f, 1.0f - c * c));
            Ps[r] = __expf(-THETA * (tc - tpre));   // prod of c, rows s0..s0+r
        } else if (d < CHUNK + NC) {
            const int j = d - CHUNK;
            const float te = tb[j * CHUNK + CHUNK - 1];
            const float tp = (j == 0) ? 0.0f : tb[j * CHUNK - 1];
            As[j] = __expf(-THETA * (te - tp));     // full-chunk decay
        }
        __syncthreads();

        // ---- load 128 rows (thread = column d), local scan from zero ----
        const float* zp = z + ((size_t)b * Sn + s0) * Dn + d;
        float v[CHUNK];              // fully unrolled -> static -> VGPRs
#pragma unroll
        for (int r = 0; r < CHUNK; ++r)
            v[r] = __builtin_nontemporal_load(zp + (size_t)r * Dn);
        float a = 0.0f;
#pragma unroll
        for (int r = 0; r < CHUNK; ++r) {
            a = fmaf(cs[r], a, ss[r] * v[r]);
            v[r] = a;
        }

        // ---- resolve incoming state E ----
        float E;
        if (k == 0) {
            E = x0[(size_t)b * Dn + d];
        } else {
            // publish aggregate, then release the flag
            __hip_atomic_store(agg + (size_t)T * Dn + d, a,
                               __ATOMIC_RELAXED, __HIP_MEMORY_SCOPE_AGENT);
            __threadfence();                     // each wave: drain to MALL
            __syncthreads();                     // all waves fenced
            if (d == 0)
                __hip_atomic_store(&flags[T], 1u, __ATOMIC_RELEASE,
                                   __HIP_MEMORY_SCOPE_AGENT);
            // decoupled lookback over same-batch predecessors
            E = 0.0f;
            float Amul = 1.0f;
            int j = k - 1;
            for (;;) {
                unsigned f;
                do {
                    f = __hip_atomic_load(&flags[(size_t)b * NC + j],
                                          __ATOMIC_ACQUIRE,
                                          __HIP_MEMORY_SCOPE_AGENT);
                    f = __builtin_amdgcn_readfirstlane(f);
                    if (f == 0u) __builtin_amdgcn_s_sleep(2);
                } while (f == 0u);
                const float* pj = ((f == 2u) ? inc : agg)
                                  + ((size_t)b * NC + j) * Dn + d;
                const float val = __hip_atomic_load(pj, __ATOMIC_RELAXED,
                                                    __HIP_MEMORY_SCOPE_AGENT);
                E = fmaf(Amul, val, E);
                if (f == 2u) break;              // consumed an inclusive: done
                Amul *= As[j];
                --j;                             // k==0 only publishes flag==2
            }
        }

        // ---- publish inclusive state (before the heavy apply/store) ----
        const float myinc = fmaf(As[k], E, a);
        __hip_atomic_store(inc + (size_t)T * Dn + d, myinc,
                           __ATOMIC_RELAXED, __HIP_MEMORY_SCOPE_AGENT);
        __threadfence();
        __syncthreads();
        if (d == 0)
            __hip_atomic_store(&flags[T], 2u, __ATOMIC_RELEASE,
                               __HIP_MEMORY_SCOPE_AGENT);

        // ---- apply carry, write output (z never re-read) ----
        float* op = out + ((size_t)b * Sn + s0) * Dn + d;
#pragma unroll
        for (int r = 0; r < CHUNK; ++r)
            __builtin_nontemporal_store(fmaf(Ps[r], E, v[r]),
                                        op + (size_t)r * Dn);
    }
}

extern "C" void kernel_launch(void* const* d_in, const int* in_sizes, int n_in,
                              void* d_out, int out_size, void* d_ws, size_t ws_size,
                              hipStream_t stream) {
    const float* t  = (const float*)d_in[0];   // [B,S,1] f32
    const float* x0 = (const float*)d_in[1];   // [B,1,D] f32
    const float* z  = (const float*)d_in[2];   // [B,S,D] f32
    float* out = (float*)d_out;                // [B,S,D] f32

    // ws: agg 2MB | inc 2MB | flags 8KB | ticket 4B   (flags+ticket contiguous)
    float*    agg    = (float*)d_ws;
    float*    inc    = agg + (size_t)NTICK * Dn;
    unsigned* flags  = (unsigned*)(inc + (size_t)NTICK * Dn);
    unsigned* ticket = flags + NTICK;

    hipMemsetAsync(flags, 0, (NTICK + 1) * sizeof(unsigned), stream);
    k_ou<<<NBLK, 256, 0, stream>>>(t, x0, z, out, agg, inc, flags, ticket);
}